// Round 12
// baseline (53.840 us; speedup 1.0000x reference)
//
#include <hip/hip_runtime.h>

// InteractionLayer (SchNet-style) — MFMA f16. Round-11 base + 3 critical-path
// cuts. MI355X gfx950.
// Shapes hardcoded: B=4, N=256, NF=H=128, K=300 filters, gamma=10, spacing=0.1.
// Block = one (b,i) row: 1024 blocks x 512 threads (8 waves: jg 0..3 x hgrp 0..1).
// Wave tile 16j x 64h. Residency register-pinned at 2 blocks/CU (rounds 3/5/8);
// kernel is latency-bound at 4 waves/SIMD -> shorten dependency chains:
//  1. ln2 folded into W2 prepack: ytile stores raw ssp_l2 (drops 16 dependent
//     v_mul per lane per chunk); z = ssp_l2 @ (ln2*W2) == ssp @ W2 exactly.
//  2. acc (GEMM1) and acc2 (GEMM2) separate (+16 regs, ~88 < 128 cap): next
//     chunk's GEMM1 MFMAs no longer serialize behind chunk c's sumv-ssp chain.
//  3. Next chunk's initial W1 B-frag prefetch issued BEFORE the barrier
//     (compiler cannot move loads across s_barrier): ~200cyc L2 latency hides
//     under barrier+GEMM2 instead of stalling GEMM1's first MFMA.
// [tripwire: FETCH > 20 MB => acc2 split spilled => revert it]
// GEMM1: rbf[64j x 320k] @ W1[320x128]; rbf exact exp-recurrence in regs;
//   K-steps restricted per sorted 16-row group (window +-12); 1-deep B-frag
//   register pipeline (proven round 11).
// GEMM2: ssp_l2(y) @ (ln2*W2) from LDS (staged, proven rounds 2/3/11).
// Main loop: 1 barrier/chunk via ytile double-buffer (proven round 10).
// ssp in log2 domain: ssp(x) = ln2*log2(0.5*exp2(x*log2e)+0.5).
//
// MFMA 16x16x32 layouts (gfx950):
//   A: lane l elem j -> A[l&15][(l>>4)*8 + j]
//   B: lane l elem j -> B[(l>>4)*8 + j][l&15]
//   D: lane l reg  r -> D[(l>>4)*4 + r][l&15]

typedef _Float16 f16x8 __attribute__((ext_vector_type(8)));
typedef float f32x4 __attribute__((ext_vector_type(4)));

__device__ __forceinline__ float exp2f_fast(float x) {
#if __has_builtin(__builtin_amdgcn_exp2f)
  return __builtin_amdgcn_exp2f(x);
#else
  return __exp2f(x);
#endif
}
__device__ __forceinline__ float log2f_fast(float x) {
#if __has_builtin(__builtin_amdgcn_logf)
  return __builtin_amdgcn_logf(x);
#else
  return __log2f(x);
#endif
}

// log2-domain ssp: log2(0.5*e^x + 0.5).  ssp(x) = ln2 * ssp_l2(x).
__device__ __forceinline__ float ssp_l2(float x) {
  return log2f_fast(fmaf(0.5f, exp2f_fast(1.44269504f * x), 0.5f));
}

// Pack W1 [300,128] -> f16 B-frag layout [10kk][8nt][64l][8j] at ws[0..40960)
// and ln2*W2 [128,128] -> [4kk][8nt][64l][8j] at ws[40960..57344).
__global__ void prep_pack(const float* __restrict__ W1, const float* __restrict__ W2,
                          unsigned short* __restrict__ ws) {
  int gid = blockIdx.x * 256 + threadIdx.x;
  if (gid < 40960) {
    int j = gid & 7, l = (gid >> 3) & 63, ntg = (gid >> 9) & 7, kk = gid >> 12;
    int k = kk * 32 + (l >> 4) * 8 + j;
    int h = ntg * 16 + (l & 15);
    float v = (k < 300) ? W1[k * 128 + h] : 0.f;
    ws[gid] = __builtin_bit_cast(unsigned short, (_Float16)v);
  } else if (gid < 57344) {
    int g2 = gid - 40960;
    int j = g2 & 7, l = (g2 >> 3) & 63, ntg = (g2 >> 9) & 7, kk = g2 >> 12;
    int k = kk * 32 + (l >> 4) * 8 + j;
    int h = ntg * 16 + (l & 15);
    ws[gid] = __builtin_bit_cast(unsigned short, (_Float16)(0.69314718f * W2[k * 128 + h]));
  }
}

__global__ __launch_bounds__(512, 4) void interaction_kernel(
    const float* __restrict__ nodef, const float* __restrict__ pos,
    const float* __restrict__ valid, const unsigned short* __restrict__ ws,
    const float* __restrict__ Wa1, const float* __restrict__ Wa2,
    const float* __restrict__ Wa3, float* __restrict__ out) {
  __shared__ __align__(16) _Float16 ytile[2][64 * 136];   // 34,816 B double-buffered
  __shared__ __align__(16) unsigned short W2pk[16384];    // 32,768 B (ln2-scaled)
  __shared__ float d_lds[256];
  __shared__ int k0arr[256];
  __shared__ unsigned short jord[256];
  __shared__ unsigned short pr[2][256];
  __shared__ int kklo[16], kkhi[16];
  __shared__ float xrow[128], h1row[128], hhrow[128], a2row[128];
  __shared__ float partial[4][128];

  const int t = threadIdx.x;
  const int bid = blockIdx.x;  // b*256 + i
  const int b = bid >> 8;

  // ---- stage (ln2*W2) fragments into LDS (16B coalesced) ----
  {
    const uint4* src = (const uint4*)(ws + 40960);
    uint4* d2 = (uint4*)W2pk;
    for (int i = t; i < 2048; i += 512) d2[i] = src[i];
  }
  if (t < 128) xrow[t] = nodef[bid * 128 + t];
  if (t < 256) {
    const float qx = pos[bid * 3 + 0], qy = pos[bid * 3 + 1], qz = pos[bid * 3 + 2];
    const float px = pos[(b * 256 + t) * 3 + 0];
    const float py = pos[(b * 256 + t) * 3 + 1];
    const float pz = pos[(b * 256 + t) * 3 + 2];
    const float dx = px - qx, dy = py - qy, dz = pz - qz;
    const float dd = sqrtf(dx * dx + dy * dy + dz * dz);
    d_lds[t] = dd;
    k0arr[t] = __float2int_rn(dd * 10.f);
  }
  __syncthreads();

  // ---- rank-sort, parallelized (proven round 9): 512 threads x 128 scans ----
  {
    const int j = t & 255, half = t >> 8;
    const int key = k0arr[j];
    int rank = 0;
    const int base = half * 128;
    for (int j2 = base; j2 < base + 128; ++j2) {
      const int k2 = k0arr[j2];
      rank += (k2 < key || (k2 == key && j2 < j)) ? 1 : 0;
    }
    pr[half][j] = (unsigned short)rank;
  }
  // h1 = x @ Wa1 (partials over 4 thread-groups)
  {
    const int hh_ = t & 127, part = t >> 7;
    float a = 0.f;
#pragma unroll 8
    for (int k = part * 32; k < part * 32 + 32; ++k) a += xrow[k] * Wa1[k * 128 + hh_];
    partial[part][hh_] = a;
  }
  __syncthreads();
  if (t < 256) jord[pr[0][t] + pr[1][t]] = (unsigned short)t;
  if (t < 128)
    h1row[t] = partial[0][t] + partial[1][t] + partial[2][t] + partial[3][t];
  __syncthreads();
  // per sorted-16-group K-step ranges (window +-12: exp(-10*1.2^2)=5.6e-7)
  if (t < 16) {
    const int base = t * 16;
    const int klo = max(0, k0arr[jord[base]] - 12);
    const int khi = min(319, k0arr[jord[base + 15]] + 12);
    kklo[t] = klo >> 5;
    kkhi[t] = (khi >> 5) + 1;
  }
  __syncthreads();

  const int wid = t >> 6, l = t & 63;
  const int jg = wid >> 1, hgrp = wid & 1;  // wave tile: 16 j-rows x 64 h-cols
  const int lr = l & 15, lq = l >> 4;
  float sumv[4] = {0.f, 0.f, 0.f, 0.f};
  f32x4 acc[4];   // GEMM1 accumulators
  f32x4 acc2[4];  // GEMM2 accumulators (separate: decouples chunk pipeline)

  // chunk-0 state, loaded pre-loop; thereafter refreshed pre-barrier
  float dd = d_lds[jord[jg * 16 + lr]];
  int lo = kklo[jg], hi = kkhi[jg];
  f16x8 nb0, nb1, nb2, nb3;
  {
    const unsigned short* p = &ws[((lo * 8 + hgrp * 4) * 64 + l) * 8];
    nb0 = *(const f16x8*)(p + 0 * 512);
    nb1 = *(const f16x8*)(p + 1 * 512);
    nb2 = *(const f16x8*)(p + 2 * 512);
    nb3 = *(const f16x8*)(p + 3 * 512);
  }

  // ---- main loop: 4 chunks of 64 sorted j's; ONE barrier per chunk ----
  for (int cc = 0; cc < 4; ++cc) {
    const int buf = cc & 1;

    // GEMM1: 16j x 64h, K-steps restricted to group window (1-deep pipeline).
#pragma unroll
    for (int r = 0; r < 4; ++r) acc[r] = f32x4{0, 0, 0, 0};
    for (int kk = lo; kk < hi; ++kk) {
      const f16x8 cb0 = nb0, cb1 = nb1, cb2 = nb2, cb3 = nb3;
      if (kk + 1 < hi) {  // wave-uniform branch
        const unsigned short* p = &ws[(((kk + 1) * 8 + hgrp * 4) * 64 + l) * 8];
        nb0 = *(const f16x8*)(p + 0 * 512);
        nb1 = *(const f16x8*)(p + 1 * 512);
        nb2 = *(const f16x8*)(p + 2 * 512);
        nb3 = *(const f16x8*)(p + 3 * 512);
      }
      // rbf via exact exp recurrence: a_j = -10*(x0-0.1j)^2;
      // a_{j+1}-a_j = 2x0-0.2j-0.1 -> v *= r, r *= e^-0.2. Underflow -> exact 0.
      const float x0 = dd - 0.1f * (float)(kk * 32 + lq * 8);
      float v = exp2f_fast(-14.4269504f * x0 * x0);                // e^{a_0}
      float r = exp2f_fast(fmaf(2.88539008f, x0, -0.144269504f));  // e^{2x0-0.1}
      f16x8 afr;
      afr[0] = (_Float16)v;
#pragma unroll
      for (int j = 1; j < 8; ++j) {
        v *= r;
        r *= 0.818730753f;  // e^-0.2
        afr[j] = (_Float16)v;
      }
      acc[0] = __builtin_amdgcn_mfma_f32_16x16x32_f16(afr, cb0, acc[0], 0, 0, 0);
      acc[1] = __builtin_amdgcn_mfma_f32_16x16x32_f16(afr, cb1, acc[1], 0, 0, 0);
      acc[2] = __builtin_amdgcn_mfma_f32_16x16x32_f16(afr, cb2, acc[2], 0, 0, 0);
      acc[3] = __builtin_amdgcn_mfma_f32_16x16x32_f16(afr, cb3, acc[3], 0, 0, 0);
    }
    // raw ssp_l2 -> y tile (ln2 folded into W2pk)
#pragma unroll
    for (int nt = 0; nt < 4; ++nt)
#pragma unroll
      for (int r = 0; r < 4; ++r)
        ytile[buf][(jg * 16 + lq * 4 + r) * 136 + hgrp * 64 + nt * 16 + lr] =
            (_Float16)ssp_l2(acc[nt][r]);

    // prep chunk cc+1 BEFORE the barrier: dd/lo/hi + initial B-frag prefetch
    if (cc < 3) {
      const int g2 = (cc + 1) * 4 + jg;
      dd = d_lds[jord[(cc + 1) * 64 + jg * 16 + lr]];
      lo = kklo[g2];
      hi = kkhi[g2];
      const unsigned short* p = &ws[((lo * 8 + hgrp * 4) * 64 + l) * 8];
      nb0 = *(const f16x8*)(p + 0 * 512);
      nb1 = *(const f16x8*)(p + 1 * 512);
      nb2 = *(const f16x8*)(p + 2 * 512);
      nb3 = *(const f16x8*)(p + 3 * 512);
    }
    __syncthreads();  // the ONLY barrier: orders this chunk's W before its R

    // GEMM2: z = y @ (ln2*W2) (dense K=128) from LDS, into acc2.
#pragma unroll
    for (int r = 0; r < 4; ++r) acc2[r] = f32x4{0, 0, 0, 0};
#pragma unroll
    for (int kk = 0; kk < 4; ++kk) {
      const f16x8 afr =
          *(const f16x8*)&ytile[buf][(jg * 16 + lr) * 136 + kk * 32 + lq * 8];
#pragma unroll
      for (int nt = 0; nt < 4; ++nt) {
        const f16x8 bfr = *(const f16x8*)&W2pk[((kk * 8 + hgrp * 4 + nt) * 64 + l) * 8];
        acc2[nt] = __builtin_amdgcn_mfma_f32_16x16x32_f16(afr, bfr, acc2[nt], 0, 0, 0);
      }
    }
    // accumulate sum_j in log2 domain (ln2 applied once in the reduction)
#pragma unroll
    for (int nt = 0; nt < 4; ++nt)
#pragma unroll
      for (int r = 0; r < 4; ++r) sumv[nt] += ssp_l2(acc2[nt][r]);
    // no second barrier: next chunk writes the OTHER buffer (round-10 proof)
  }

  // ---- reduce sum_j partials (16 per h-column); f32 scratch over ytile[0].
  {
    float* red = (float*)&ytile[0][0];
#pragma unroll
    for (int nt = 0; nt < 4; ++nt)
      red[(jg * 4 + lq) * 128 + hgrp * 64 + nt * 16 + lr] = 0.69314718f * sumv[nt];
  }
  __syncthreads();
  if (t < 128) {
    const float* red = (const float*)&ytile[0][0];
    float s = 0.f;
#pragma unroll
    for (int q = 0; q < 16; ++q) s += red[q * 128 + t];
    hhrow[t] = h1row[t] * s;  // CFConv: h * sum_j filt
  }
  __syncthreads();
  // a2 = ssp(hh @ Wa2)
  {
    const int hh_ = t & 127, part = t >> 7;
    float a = 0.f;
#pragma unroll 8
    for (int k = part * 32; k < part * 32 + 32; ++k) a += hhrow[k] * Wa2[k * 128 + hh_];
    partial[part][hh_] = a;
  }
  __syncthreads();
  if (t < 128)
    a2row[t] = 0.69314718f *
               ssp_l2(partial[0][t] + partial[1][t] + partial[2][t] + partial[3][t]);
  __syncthreads();
  // out = x + (a2 @ Wa3) * valid
  {
    const int hh_ = t & 127, part = t >> 7;
    float a = 0.f;
#pragma unroll 8
    for (int k = part * 32; k < part * 32 + 32; ++k) a += a2row[k] * Wa3[k * 128 + hh_];
    partial[part][hh_] = a;
  }
  __syncthreads();
  if (t < 128)
    out[bid * 128 + t] =
        xrow[t] + (partial[0][t] + partial[1][t] + partial[2][t] + partial[3][t]) * valid[bid];
}

extern "C" void kernel_launch(void* const* d_in, const int* in_sizes, int n_in,
                              void* d_out, int out_size, void* d_ws, size_t ws_size,
                              hipStream_t stream) {
  const float* nodef = (const float*)d_in[0];
  const float* pos   = (const float*)d_in[1];
  const float* valid = (const float*)d_in[2];
  const float* W1    = (const float*)d_in[3];
  const float* W2    = (const float*)d_in[4];
  const float* Wa1   = (const float*)d_in[5];
  const float* Wa2   = (const float*)d_in[6];
  const float* Wa3   = (const float*)d_in[7];
  float* outp = (float*)d_out;
  unsigned short* wsp = (unsigned short*)d_ws;  // 57,344 f16 = 114,688 B

  prep_pack<<<224, 256, 0, stream>>>(W1, W2, wsp);
  interaction_kernel<<<1024, 512, 0, stream>>>(nodef, pos, valid, wsp,
                                               Wa1, Wa2, Wa3, outp);
}

// Round 14
// 51.651 us; speedup vs baseline: 1.0424x; 1.0424x over previous
//
#include <hip/hip_runtime.h>

// InteractionLayer (SchNet-style) — MFMA f16. Round-12 base + VALU-count cuts.
// MI355X gfx950. Shapes hardcoded: B=4, N=256, NF=H=128, K=300, gamma=10, dk=0.1.
// Block = one (b,i) row: 1024 blocks x 512 threads (8 waves: jg 0..3 x hgrp 0..1).
// Wave tile 16j x 64h. Residency register-pinned at 2 blocks/CU (rounds 3/5/8);
// rounds 11/12 showed latency shuffling is exhausted -> this round cuts VALU
// ISSUE COUNT (measured 61% busy, ~2.6x my source-level count -> generated-code
// overhead):
//  1. log2e folded into W1pk (=log2e*W1) and W2pk (=W2, since ln2*log2e==1):
//     both ssp evals become log2(0.5*exp2(acc)+0.5) with NO per-element mul.
//  2. GEMM1 prefetch pipeline (16 v_mov + branch per kk) replaced by straight-
//     line: load both B-frag sets up front, MFMA set0, set1 if n>1, rare tail.
//  3. A-frag f32->f16 via v_cvt_pkrtz (4 pack ops instead of 8 scalar cvt).
//     [round-13 fix: builtin returns __fp16x2 -> bit_cast to _Float16x2]
// [tripwire: FETCH > 20 MB => spill => revert]
// GEMM1: rbf[64j x 320k] @ W1'[320x128]; rbf exact exp-recurrence in regs;
//   K-steps per sorted 16-row group (window +-12), n in {1,2,3}.
// GEMM2: y' @ W2 from LDS (staged). Main loop: 1 barrier/chunk (ytile dbuf).
// sum_j kept in log2 domain; ln2 applied once in the reduction.
//
// MFMA 16x16x32 layouts (gfx950):
//   A: lane l elem j -> A[l&15][(l>>4)*8 + j]
//   B: lane l elem j -> B[(l>>4)*8 + j][l&15]
//   D: lane l reg  r -> D[(l>>4)*4 + r][l&15]

typedef _Float16 f16x8 __attribute__((ext_vector_type(8)));
typedef _Float16 f16x2 __attribute__((ext_vector_type(2)));
typedef float f32x4 __attribute__((ext_vector_type(4)));

__device__ __forceinline__ float exp2f_fast(float x) {
#if __has_builtin(__builtin_amdgcn_exp2f)
  return __builtin_amdgcn_exp2f(x);
#else
  return __exp2f(x);
#endif
}
__device__ __forceinline__ float log2f_fast(float x) {
#if __has_builtin(__builtin_amdgcn_logf)
  return __builtin_amdgcn_logf(x);
#else
  return __log2f(x);
#endif
}

// pre-scaled log2-domain ssp: input a = log2e*x; returns log2(0.5*2^a+0.5)
// = ssp(x)/ln2. NO multiply inside (log2e folded into the MFMA weights).
__device__ __forceinline__ float ssp_l2p(float a) {
  return log2f_fast(fmaf(0.5f, exp2f_fast(a), 0.5f));
}
// natural-domain variant (epilogue only, few calls)
__device__ __forceinline__ float ssp_l2(float x) {
  return ssp_l2p(1.44269504f * x);
}

__device__ __forceinline__ f16x2 pk2(float a, float b) {
#if __has_builtin(__builtin_amdgcn_cvt_pkrtz)
  return __builtin_bit_cast(f16x2, __builtin_amdgcn_cvt_pkrtz(a, b));
#else
  f16x2 t;
  t.x = (_Float16)a;
  t.y = (_Float16)b;
  return t;
#endif
}

// rbf A-fragment for k-base kk*32+lq*8 via exact exp recurrence:
// a_j = -10*(x0-0.1j)^2; a_{j+1}-a_j = 2x0-0.2j-0.1 -> v*=r, r*=e^-0.2.
// Underflow -> exact 0 (values outside window are < 1e-19).
__device__ __forceinline__ f16x8 rbf8(float dd, int kk, int lq) {
  const float x0 = dd - 0.1f * (float)(kk * 32 + lq * 8);
  float v = exp2f_fast(-14.4269504f * x0 * x0);                // e^{a_0}
  float r = exp2f_fast(fmaf(2.88539008f, x0, -0.144269504f));  // e^{2x0-0.1}
  float w0 = v;
  v *= r; r *= 0.818730753f; float w1 = v;
  v *= r; r *= 0.818730753f; float w2 = v;
  v *= r; r *= 0.818730753f; float w3 = v;
  v *= r; r *= 0.818730753f; float w4 = v;
  v *= r; r *= 0.818730753f; float w5 = v;
  v *= r; r *= 0.818730753f; float w6 = v;
  v *= r;                    float w7 = v;
  union { f16x8 v8; f16x2 p[4]; } u;
  u.p[0] = pk2(w0, w1);
  u.p[1] = pk2(w2, w3);
  u.p[2] = pk2(w4, w5);
  u.p[3] = pk2(w6, w7);
  return u.v8;
}

// Pack log2e*W1 [300,128] -> f16 B-frag layout [10kk][8nt][64l][8j] at ws[0..40960)
// and W2 [128,128] -> [4kk][8nt][64l][8j] at ws[40960..57344).
__global__ void prep_pack(const float* __restrict__ W1, const float* __restrict__ W2,
                          unsigned short* __restrict__ ws) {
  int gid = blockIdx.x * 256 + threadIdx.x;
  if (gid < 40960) {
    int j = gid & 7, l = (gid >> 3) & 63, ntg = (gid >> 9) & 7, kk = gid >> 12;
    int k = kk * 32 + (l >> 4) * 8 + j;
    int h = ntg * 16 + (l & 15);
    float v = (k < 300) ? 1.44269504f * W1[k * 128 + h] : 0.f;
    ws[gid] = __builtin_bit_cast(unsigned short, (_Float16)v);
  } else if (gid < 57344) {
    int g2 = gid - 40960;
    int j = g2 & 7, l = (g2 >> 3) & 63, ntg = (g2 >> 9) & 7, kk = g2 >> 12;
    int k = kk * 32 + (l >> 4) * 8 + j;
    int h = ntg * 16 + (l & 15);
    ws[gid] = __builtin_bit_cast(unsigned short, (_Float16)W2[k * 128 + h]);
  }
}

__global__ __launch_bounds__(512, 4) void interaction_kernel(
    const float* __restrict__ nodef, const float* __restrict__ pos,
    const float* __restrict__ valid, const unsigned short* __restrict__ ws,
    const float* __restrict__ Wa1, const float* __restrict__ Wa2,
    const float* __restrict__ Wa3, float* __restrict__ out) {
  __shared__ __align__(16) _Float16 ytile[2][64 * 136];   // 34,816 B double-buffered
  __shared__ __align__(16) unsigned short W2pk[16384];    // 32,768 B
  __shared__ float d_lds[256];
  __shared__ int k0arr[256];
  __shared__ unsigned short jord[256];
  __shared__ unsigned short pr[2][256];
  __shared__ int kklo[16], kkhi[16];
  __shared__ float xrow[128], h1row[128], hhrow[128], a2row[128];
  __shared__ float partial[4][128];

  const int t = threadIdx.x;
  const int bid = blockIdx.x;  // b*256 + i
  const int b = bid >> 8;

  // ---- stage W2 fragments into LDS (16B coalesced) ----
  {
    const uint4* src = (const uint4*)(ws + 40960);
    uint4* d2 = (uint4*)W2pk;
    for (int i = t; i < 2048; i += 512) d2[i] = src[i];
  }
  if (t < 128) xrow[t] = nodef[bid * 128 + t];
  if (t < 256) {
    const float qx = pos[bid * 3 + 0], qy = pos[bid * 3 + 1], qz = pos[bid * 3 + 2];
    const float px = pos[(b * 256 + t) * 3 + 0];
    const float py = pos[(b * 256 + t) * 3 + 1];
    const float pz = pos[(b * 256 + t) * 3 + 2];
    const float dx = px - qx, dy = py - qy, dz = pz - qz;
    const float dd = sqrtf(dx * dx + dy * dy + dz * dz);
    d_lds[t] = dd;
    k0arr[t] = __float2int_rn(dd * 10.f);
  }
  __syncthreads();

  // ---- rank-sort, parallelized (proven round 9): 512 threads x 128 scans ----
  {
    const int j = t & 255, half = t >> 8;
    const int key = k0arr[j];
    int rank = 0;
    const int base = half * 128;
    for (int j2 = base; j2 < base + 128; ++j2) {
      const int k2 = k0arr[j2];
      rank += (k2 < key || (k2 == key && j2 < j)) ? 1 : 0;
    }
    pr[half][j] = (unsigned short)rank;
  }
  // h1 = x @ Wa1 (partials over 4 thread-groups)
  {
    const int hh_ = t & 127, part = t >> 7;
    float a = 0.f;
#pragma unroll 8
    for (int k = part * 32; k < part * 32 + 32; ++k) a += xrow[k] * Wa1[k * 128 + hh_];
    partial[part][hh_] = a;
  }
  __syncthreads();
  if (t < 256) jord[pr[0][t] + pr[1][t]] = (unsigned short)t;
  if (t < 128)
    h1row[t] = partial[0][t] + partial[1][t] + partial[2][t] + partial[3][t];
  __syncthreads();
  // per sorted-16-group K-step ranges (window +-12: exp(-10*1.2^2)=5.6e-7)
  if (t < 16) {
    const int base = t * 16;
    const int klo = max(0, k0arr[jord[base]] - 12);
    const int khi = min(319, k0arr[jord[base + 15]] + 12);
    kklo[t] = klo >> 5;
    kkhi[t] = (khi >> 5) + 1;
  }
  __syncthreads();

  const int wid = t >> 6, l = t & 63;
  const int jg = wid >> 1, hgrp = wid & 1;  // wave tile: 16 j-rows x 64 h-cols
  const int lr = l & 15, lq = l >> 4;
  float sumv[4] = {0.f, 0.f, 0.f, 0.f};
  f32x4 acc[4];   // GEMM1 accumulators
  f32x4 acc2[4];  // GEMM2 accumulators

  // ---- main loop: 4 chunks of 64 sorted j's; ONE barrier per chunk ----
  for (int cc = 0; cc < 4; ++cc) {
    const int buf = cc & 1;
    const int g = cc * 4 + jg;
    const float dd = d_lds[jord[cc * 64 + jg * 16 + lr]];
    const int lo = kklo[g];
    const int n = kkhi[g] - lo;  // wave-uniform, 1..3

    // GEMM1: straight-line for the common n in {1,2}; rare tail loop for n>2.
    // Both B-frag sets load before the first MFMA (latency hidden, no v_mov
    // rotation, no per-iteration branch).
#pragma unroll
    for (int r = 0; r < 4; ++r) acc[r] = f32x4{0, 0, 0, 0};
    const unsigned short* pb = &ws[((lo * 8 + hgrp * 4) * 64 + l) * 8];
    const f16x8 c00 = *(const f16x8*)(pb + 0 * 512);
    const f16x8 c01 = *(const f16x8*)(pb + 1 * 512);
    const f16x8 c02 = *(const f16x8*)(pb + 2 * 512);
    const f16x8 c03 = *(const f16x8*)(pb + 3 * 512);
    f16x8 c10, c11, c12, c13;
    if (n > 1) {  // wave-uniform
      c10 = *(const f16x8*)(pb + 4096 + 0 * 512);
      c11 = *(const f16x8*)(pb + 4096 + 1 * 512);
      c12 = *(const f16x8*)(pb + 4096 + 2 * 512);
      c13 = *(const f16x8*)(pb + 4096 + 3 * 512);
    }
    {
      const f16x8 af0 = rbf8(dd, lo, lq);
      acc[0] = __builtin_amdgcn_mfma_f32_16x16x32_f16(af0, c00, acc[0], 0, 0, 0);
      acc[1] = __builtin_amdgcn_mfma_f32_16x16x32_f16(af0, c01, acc[1], 0, 0, 0);
      acc[2] = __builtin_amdgcn_mfma_f32_16x16x32_f16(af0, c02, acc[2], 0, 0, 0);
      acc[3] = __builtin_amdgcn_mfma_f32_16x16x32_f16(af0, c03, acc[3], 0, 0, 0);
    }
    if (n > 1) {
      const f16x8 af1 = rbf8(dd, lo + 1, lq);
      acc[0] = __builtin_amdgcn_mfma_f32_16x16x32_f16(af1, c10, acc[0], 0, 0, 0);
      acc[1] = __builtin_amdgcn_mfma_f32_16x16x32_f16(af1, c11, acc[1], 0, 0, 0);
      acc[2] = __builtin_amdgcn_mfma_f32_16x16x32_f16(af1, c12, acc[2], 0, 0, 0);
      acc[3] = __builtin_amdgcn_mfma_f32_16x16x32_f16(af1, c13, acc[3], 0, 0, 0);
    }
    for (int kk = lo + 2; kk < lo + n; ++kk) {  // rare (n==3)
      const unsigned short* p = pb + (kk - lo) * 4096;
      const f16x8 d0 = *(const f16x8*)(p + 0 * 512);
      const f16x8 d1 = *(const f16x8*)(p + 1 * 512);
      const f16x8 d2 = *(const f16x8*)(p + 2 * 512);
      const f16x8 d3 = *(const f16x8*)(p + 3 * 512);
      const f16x8 af = rbf8(dd, kk, lq);
      acc[0] = __builtin_amdgcn_mfma_f32_16x16x32_f16(af, d0, acc[0], 0, 0, 0);
      acc[1] = __builtin_amdgcn_mfma_f32_16x16x32_f16(af, d1, acc[1], 0, 0, 0);
      acc[2] = __builtin_amdgcn_mfma_f32_16x16x32_f16(af, d2, acc[2], 0, 0, 0);
      acc[3] = __builtin_amdgcn_mfma_f32_16x16x32_f16(af, d3, acc[3], 0, 0, 0);
    }
    // y' = ssp_l2p(acc) -> y tile (acc is log2e-scaled via W1pk; no mul)
#pragma unroll
    for (int nt = 0; nt < 4; ++nt)
#pragma unroll
      for (int r = 0; r < 4; ++r)
        ytile[buf][(jg * 16 + lq * 4 + r) * 136 + hgrp * 64 + nt * 16 + lr] =
            (_Float16)ssp_l2p(acc[nt][r]);
    __syncthreads();  // the ONLY barrier: orders this chunk's W before its R

    // GEMM2: acc2 = y' @ W2 (dense K=128) from LDS. Since y' = ssp/ln2 and
    // we want log2e*z = log2e*(ssp@W2) = y' @ W2, W2pk is UNSCALED W2.
#pragma unroll
    for (int r = 0; r < 4; ++r) acc2[r] = f32x4{0, 0, 0, 0};
#pragma unroll
    for (int kk = 0; kk < 4; ++kk) {
      const f16x8 afr =
          *(const f16x8*)&ytile[buf][(jg * 16 + lr) * 136 + kk * 32 + lq * 8];
#pragma unroll
      for (int nt = 0; nt < 4; ++nt) {
        const f16x8 bfr = *(const f16x8*)&W2pk[((kk * 8 + hgrp * 4 + nt) * 64 + l) * 8];
        acc2[nt] = __builtin_amdgcn_mfma_f32_16x16x32_f16(afr, bfr, acc2[nt], 0, 0, 0);
      }
    }
    // accumulate sum_j in log2 domain (ln2 applied once in the reduction)
#pragma unroll
    for (int nt = 0; nt < 4; ++nt)
#pragma unroll
      for (int r = 0; r < 4; ++r) sumv[nt] += ssp_l2p(acc2[nt][r]);
    // no second barrier: next chunk writes the OTHER buffer (round-10 proof)
  }

  // ---- reduce sum_j partials (16 per h-column); f32 scratch over ytile[0].
  {
    float* red = (float*)&ytile[0][0];
#pragma unroll
    for (int nt = 0; nt < 4; ++nt)
      red[(jg * 4 + lq) * 128 + hgrp * 64 + nt * 16 + lr] = 0.69314718f * sumv[nt];
  }
  __syncthreads();
  if (t < 128) {
    const float* red = (const float*)&ytile[0][0];
    float s = 0.f;
#pragma unroll
    for (int q = 0; q < 16; ++q) s += red[q * 128 + t];
    hhrow[t] = h1row[t] * s;  // CFConv: h * sum_j filt
  }
  __syncthreads();
  // a2 = ssp(hh @ Wa2)
  {
    const int hh_ = t & 127, part = t >> 7;
    float a = 0.f;
#pragma unroll 8
    for (int k = part * 32; k < part * 32 + 32; ++k) a += hhrow[k] * Wa2[k * 128 + hh_];
    partial[part][hh_] = a;
  }
  __syncthreads();
  if (t < 128)
    a2row[t] = 0.69314718f *
               ssp_l2(partial[0][t] + partial[1][t] + partial[2][t] + partial[3][t]);
  __syncthreads();
  // out = x + (a2 @ Wa3) * valid
  {
    const int hh_ = t & 127, part = t >> 7;
    float a = 0.f;
#pragma unroll 8
    for (int k = part * 32; k < part * 32 + 32; ++k) a += a2row[k] * Wa3[k * 128 + hh_];
    partial[part][hh_] = a;
  }
  __syncthreads();
  if (t < 128)
    out[bid * 128 + t] =
        xrow[t] + (partial[0][t] + partial[1][t] + partial[2][t] + partial[3][t]) * valid[bid];
}

extern "C" void kernel_launch(void* const* d_in, const int* in_sizes, int n_in,
                              void* d_out, int out_size, void* d_ws, size_t ws_size,
                              hipStream_t stream) {
  const float* nodef = (const float*)d_in[0];
  const float* pos   = (const float*)d_in[1];
  const float* valid = (const float*)d_in[2];
  const float* W1    = (const float*)d_in[3];
  const float* W2    = (const float*)d_in[4];
  const float* Wa1   = (const float*)d_in[5];
  const float* Wa2   = (const float*)d_in[6];
  const float* Wa3   = (const float*)d_in[7];
  float* outp = (float*)d_out;
  unsigned short* wsp = (unsigned short*)d_ws;  // 57,344 f16 = 114,688 B

  prep_pack<<<224, 256, 0, stream>>>(W1, W2, wsp);
  interaction_kernel<<<1024, 512, 0, stream>>>(nodef, pos, valid, wsp,
                                               Wa1, Wa2, Wa3, outp);
}